// Round 6
// baseline (431.103 us; speedup 1.0000x reference)
//
#include <hip/hip_runtime.h>
#include <hip/hip_bf16.h>

// ---------------------------------------------------------------------------
// ResidualBlock: GMMConv(x)->BN->ELU->GMMConv->BN  +  GMMConv_sc(x)->BN ; ELU
// N=50000, E=800000, C=64, K_main=5, K_sc=1. fp32.
// Round 6: de-atomic'd scatter (pos recorded in hist); weights fused into
// scatter (writes both layers' 32B agg-records directly, wgt passes deleted);
// agg unrolled x8 (8 gathers in flight); GEMM 128x64 tile, 8x4 micro,
// strided-row fragments (bank-conflict-free); parallel detect.
// ---------------------------------------------------------------------------

#define EPS_SIGMA 1e-15f
#define BN_EPS    1e-5f

// --- dtype detect: int64 edge_index has all-zero high words -----------------
__global__ void detect_kernel(const void* ei, int* flag) {
  const int* p = (const int*)ei;
  __shared__ int bad;
  if (threadIdx.x == 0) bad = 0;
  __syncthreads();
  if (p[threadIdx.x * 2 + 1] != 0) atomicAdd(&bad, 1);
  __syncthreads();
  if (threadIdx.x == 0) *flag = (bad == 0);  // 1 => int64 layout
}

__device__ __forceinline__ int load_idx(const void* ei, size_t pos, int is64) {
  if (is64) return (int)((const long long*)ei)[pos];
  return ((const int*)ei)[pos];
}

// --- CSR build: hist also records each edge's within-bucket position --------
__global__ void hist_kernel(const void* ei, int E, const int* flag, int* cnt,
                            int* __restrict__ pos) {
  int e = blockIdx.x * blockDim.x + threadIdx.x;
  if (e >= E) return;
  int d = load_idx(ei, (size_t)E + e, *flag);
  pos[e] = atomicAdd(&cnt[d], 1);
}

__global__ __launch_bounds__(256) void scan1(const int* __restrict__ cnt,
                                             int* __restrict__ row_ptr,
                                             int* __restrict__ partials, int n) {
  int tid = threadIdx.x;
  int base = blockIdx.x * 2048 + tid * 8;
  int v[8], pre[8];
  int run = 0;
#pragma unroll
  for (int j = 0; j < 8; ++j) {
    int idx = base + j;
    v[j] = (idx < n) ? cnt[idx] : 0;
    pre[j] = run;
    run += v[j];
  }
  __shared__ int sd[256];
  sd[tid] = run;
  __syncthreads();
  for (int off = 1; off < 256; off <<= 1) {
    int t = (tid >= off) ? sd[tid - off] : 0;
    __syncthreads();
    sd[tid] += t;
    __syncthreads();
  }
  int excl = sd[tid] - run;
#pragma unroll
  for (int j = 0; j < 8; ++j) {
    int idx = base + j;
    if (idx < n) row_ptr[idx] = excl + pre[j];
  }
  if (tid == 255) partials[blockIdx.x] = sd[255];
}

__global__ void scan2(int* partials, int nb, int* row_ptr, int n) {
  __shared__ int sd[256];
  int tid = threadIdx.x;
  int v = (tid < nb) ? partials[tid] : 0;
  sd[tid] = v;
  __syncthreads();
  for (int off = 1; off < 256; off <<= 1) {
    int t = (tid >= off) ? sd[tid - off] : 0;
    __syncthreads();
    sd[tid] += t;
    __syncthreads();
  }
  if (tid < nb) partials[tid] = sd[tid] - v;
  if (tid == nb - 1) row_ptr[n] = sd[tid];
}

__global__ void scan3(int* __restrict__ row_ptr, const int* __restrict__ partials, int n) {
  int i = blockIdx.x * 256 + threadIdx.x;
  if (i < n) row_ptr[i] += partials[i >> 11];
}

// --- scatter + gaussian weights fused: writes both layers' edge records -----
// wbuf1 rec: {w1_0..w1_3},{w1_4, w_sc, src_bits, 0}   (KT=6 for layer1+sc)
// wbuf2 rec: {w2_0..w2_3},{w2_4, 0,    src_bits, 0}   (KT=5 for layer2)
__global__ __launch_bounds__(256) void scatter_wgt(
    const void* ei, const float* __restrict__ ea, int E, const int* flag,
    const int* __restrict__ row_ptr, const int* __restrict__ pos,
    const float* __restrict__ mu1, const float* __restrict__ sig1,
    const float* __restrict__ mus, const float* __restrict__ sigs,
    const float* __restrict__ mu2, const float* __restrict__ sig2,
    float* __restrict__ wbuf1, float* __restrict__ wbuf2) {
  int e = blockIdx.x * 256 + threadIdx.x;
  if (e >= E) return;
  int is64 = *flag;
  int s = load_idx(ei, (size_t)e, is64);
  int d = load_idx(ei, (size_t)E + e, is64);
  int slot = row_ptr[d] + pos[e];
  float p = ea[e];
  float w1[6], w2[5];
#pragma unroll
  for (int k = 0; k < 5; ++k) {
    float sg = sig1[k], df = p - mu1[k];
    w1[k] = __expf(-0.5f / (EPS_SIGMA + sg * sg) * df * df);
  }
  {
    float sg = sigs[0], df = p - mus[0];
    w1[5] = __expf(-0.5f / (EPS_SIGMA + sg * sg) * df * df);
  }
#pragma unroll
  for (int k = 0; k < 5; ++k) {
    float sg = sig2[k], df = p - mu2[k];
    w2[k] = __expf(-0.5f / (EPS_SIGMA + sg * sg) * df * df);
  }
  float sb = __int_as_float(s);
  float4* o1 = (float4*)wbuf1;
  o1[(size_t)slot * 2 + 0] = make_float4(w1[0], w1[1], w1[2], w1[3]);
  o1[(size_t)slot * 2 + 1] = make_float4(w1[4], w1[5], sb, 0.f);
  float4* o2 = (float4*)wbuf2;
  o2[(size_t)slot * 2 + 0] = make_float4(w2[0], w2[1], w2[2], w2[3]);
  o2[(size_t)slot * 2 + 1] = make_float4(w2[4], 0.f, sb, 0.f);
}

// --- aggregation: wave per node, lane = channel, 8 edges in flight ----------
template <int KT>
__device__ __forceinline__ void agg_fma(float* acc, float4 wa, float4 wb, float xv) {
  acc[0] = fmaf(wa.x, xv, acc[0]);
  if (KT > 1) acc[1] = fmaf(wa.y, xv, acc[1]);
  if (KT > 2) acc[2] = fmaf(wa.z, xv, acc[2]);
  if (KT > 3) acc[3] = fmaf(wa.w, xv, acc[3]);
  if (KT > 4) acc[4] = fmaf(wb.x, xv, acc[4]);
  if (KT > 5) acc[5] = fmaf(wb.y, xv, acc[5]);
}

template <int KT>
__global__ __launch_bounds__(256) void agg_pre(const float* __restrict__ feat,
                                               const int* __restrict__ row_ptr,
                                               const float* __restrict__ wbuf,
                                               float* __restrict__ out, int n, int ldo) {
  int node = blockIdx.x * 4 + (threadIdx.x >> 6);
  int lane = threadIdx.x & 63;
  if (node >= n) return;
  int beg = row_ptr[node], end = row_ptr[node + 1];
  float acc[KT];
#pragma unroll
  for (int k = 0; k < KT; ++k) acc[k] = 0.f;
  const float4* w4 = (const float4*)wbuf;
  int i = beg;
  for (; i + 8 <= end; i += 8) {
    float4 wa[8], wb[8];
#pragma unroll
    for (int j = 0; j < 8; ++j) {
      wa[j] = w4[(size_t)(i + j) * 2 + 0];
      wb[j] = w4[(size_t)(i + j) * 2 + 1];
    }
    float xv[8];
#pragma unroll
    for (int j = 0; j < 8; ++j)
      xv[j] = feat[(size_t)__float_as_int(wb[j].z) * 64 + lane];
#pragma unroll
    for (int j = 0; j < 8; ++j) agg_fma<KT>(acc, wa[j], wb[j], xv[j]);
  }
  for (; i + 4 <= end; i += 4) {
    float4 wa[4], wb[4];
#pragma unroll
    for (int j = 0; j < 4; ++j) {
      wa[j] = w4[(size_t)(i + j) * 2 + 0];
      wb[j] = w4[(size_t)(i + j) * 2 + 1];
    }
    float xv[4];
#pragma unroll
    for (int j = 0; j < 4; ++j)
      xv[j] = feat[(size_t)__float_as_int(wb[j].z) * 64 + lane];
#pragma unroll
    for (int j = 0; j < 4; ++j) agg_fma<KT>(acc, wa[j], wb[j], xv[j]);
  }
  for (; i < end; ++i) {
    float4 wa = w4[(size_t)i * 2 + 0], wb = w4[(size_t)i * 2 + 1];
    float xv = feat[(size_t)__float_as_int(wb.z) * 64 + lane];
    agg_fma<KT>(acc, wa, wb, xv);
  }
  int degi = end - beg;
  float invdeg = 1.0f / (float)(degi > 1 ? degi : 1);
  size_t o = (size_t)node * ldo + lane;
#pragma unroll
  for (int k = 0; k < KT; ++k) out[o + k * 64] = acc[k] * invdeg;
}

// --- weight prep: Bout[(K*64+64) x 64] = [rearranged G ; root] ---------------
__global__ void prep_cat(const float* __restrict__ g, const float* __restrict__ root,
                         float* __restrict__ Bout, int K) {
  int idx = blockIdx.x * 256 + threadIdx.x;
  int total = (K + 1) * 64 * 64;
  if (idx >= total) return;
  int r = idx >> 6, c = idx & 63;
  float v;
  if (r < K * 64) {
    int k = r >> 6, i = r & 63;
    v = g[i * (K * 64) + k * 64 + c];
  } else {
    v = root[(r - K * 64) * 64 + c];
  }
  Bout[idx] = v;
}

// --- GEMM: C[M,64] = [A1(K1)|A2(64)]@B + bias ; fused BN stats --------------
// 128x64 tile, 8x4 micro-tile, rows strided by 16 (bank-conflict-free As).
__global__ __launch_bounds__(256) void gemm_fused(const float* __restrict__ A1, int lda1,
                                                  int K1, const float* __restrict__ A2,
                                                  const float* __restrict__ B,
                                                  const float* __restrict__ bias,
                                                  float* __restrict__ C, int M,
                                                  float* sums, float* sumsq) {
  __shared__ float As[128][68];
  __shared__ float Bs[64][64];
  __shared__ float red[16][64];
  int tile_m = blockIdx.x * 128;
  int tid = threadIdx.x, tx = tid & 15, ty = tid >> 4;
  float acc[8][4] = {};
  int nch = K1 >> 6;
  for (int ch = 0; ch <= nch; ++ch) {
    const float* Ap;
    int lda, kb;
    if (ch < nch) { Ap = A1; lda = lda1; kb = ch * 64; }
    else          { Ap = A2; lda = 64;   kb = 0; }
#pragma unroll
    for (int i = 0; i < 8; ++i) {
      int idx = tid + i * 256, r = idx >> 4, c4 = idx & 15;
      float4 v = make_float4(0.f, 0.f, 0.f, 0.f);
      if (tile_m + r < M) v = *(const float4*)&Ap[(size_t)(tile_m + r) * lda + kb + c4 * 4];
      *(float4*)&As[r][c4 * 4] = v;
    }
#pragma unroll
    for (int i = 0; i < 4; ++i) {
      int idx = tid + i * 256, r = idx >> 4, c4 = idx & 15;
      *(float4*)&Bs[r][c4 * 4] = *(const float4*)&B[(size_t)(ch * 64 + r) * 64 + c4 * 4];
    }
    __syncthreads();
#pragma unroll
    for (int k = 0; k < 64; k += 4) {
      float4 b0 = *(const float4*)&Bs[k + 0][tx * 4];
      float4 b1v = *(const float4*)&Bs[k + 1][tx * 4];
      float4 b2 = *(const float4*)&Bs[k + 2][tx * 4];
      float4 b3 = *(const float4*)&Bs[k + 3][tx * 4];
#pragma unroll
      for (int i = 0; i < 8; ++i) {
        float4 a = *(const float4*)&As[ty + i * 16][k];
        acc[i][0] = fmaf(a.x, b0.x, acc[i][0]);
        acc[i][1] = fmaf(a.x, b0.y, acc[i][1]);
        acc[i][2] = fmaf(a.x, b0.z, acc[i][2]);
        acc[i][3] = fmaf(a.x, b0.w, acc[i][3]);
        acc[i][0] = fmaf(a.y, b1v.x, acc[i][0]);
        acc[i][1] = fmaf(a.y, b1v.y, acc[i][1]);
        acc[i][2] = fmaf(a.y, b1v.z, acc[i][2]);
        acc[i][3] = fmaf(a.y, b1v.w, acc[i][3]);
        acc[i][0] = fmaf(a.z, b2.x, acc[i][0]);
        acc[i][1] = fmaf(a.z, b2.y, acc[i][1]);
        acc[i][2] = fmaf(a.z, b2.z, acc[i][2]);
        acc[i][3] = fmaf(a.z, b2.w, acc[i][3]);
        acc[i][0] = fmaf(a.w, b3.x, acc[i][0]);
        acc[i][1] = fmaf(a.w, b3.y, acc[i][1]);
        acc[i][2] = fmaf(a.w, b3.z, acc[i][2]);
        acc[i][3] = fmaf(a.w, b3.w, acc[i][3]);
      }
    }
    __syncthreads();
  }
  float cs[4] = {}, cq[4] = {};
#pragma unroll
  for (int i = 0; i < 8; ++i) {
    int r = tile_m + ty + i * 16;
    if (r < M) {
      int cc = tx * 4;
      float ov[4];
#pragma unroll
      for (int j = 0; j < 4; ++j) {
        ov[j] = acc[i][j] + bias[cc + j];
        cs[j] += ov[j];
        cq[j] = fmaf(ov[j], ov[j], cq[j]);
      }
      *(float4*)&C[(size_t)r * 64 + cc] = make_float4(ov[0], ov[1], ov[2], ov[3]);
    }
  }
#pragma unroll
  for (int j = 0; j < 4; ++j) red[ty][tx * 4 + j] = cs[j];
  __syncthreads();
  if (tid < 64) {
    float t = 0.f;
#pragma unroll
    for (int g = 0; g < 16; ++g) t += red[g][tid];
    atomicAdd(&sums[tid], t);
  }
  __syncthreads();
#pragma unroll
  for (int j = 0; j < 4; ++j) red[ty][tx * 4 + j] = cq[j];
  __syncthreads();
  if (tid < 64) {
    float t = 0.f;
#pragma unroll
    for (int g = 0; g < 16; ++g) t += red[g][tid];
    atomicAdd(&sumsq[tid], t);
  }
}

// --- batchnorm scale/shift + epilogues --------------------------------------
__global__ void bn_final(const float* sum, const float* sumsq, const float* gamma,
                         const float* beta, int n, float* scale, float* shift) {
  int c = threadIdx.x;
  float m = sum[c] / (float)n;
  float v = sumsq[c] / (float)n - m * m;
  float r = rsqrtf(v + BN_EPS);
  float s = r * gamma[c];
  scale[c] = s;
  shift[c] = beta[c] - m * s;
}

__global__ void norm_elu(float* h, const float* __restrict__ scale,
                         const float* __restrict__ shift, int total) {
  int i = blockIdx.x * 256 + threadIdx.x;
  if (i >= total) return;
  int c = i & 63;
  float v = h[i] * scale[c] + shift[c];
  h[i] = v > 0.f ? v : expm1f(v);
}

__global__ void final_kernel(const float* __restrict__ h2, const float* __restrict__ sc,
                             const float* __restrict__ s2, const float* __restrict__ t2,
                             const float* __restrict__ ss, const float* __restrict__ ts,
                             float* __restrict__ out, int total) {
  int i = blockIdx.x * 256 + threadIdx.x;
  if (i >= total) return;
  int c = i & 63;
  float v = h2[i] * s2[c] + t2[c] + sc[i] * ss[c] + ts[c];
  out[i] = v > 0.f ? v : expm1f(v);
}

// ---------------------------------------------------------------------------
extern "C" void kernel_launch(void* const* d_in, const int* in_sizes, int n_in,
                              void* d_out, int out_size, void* d_ws, size_t ws_size,
                              hipStream_t stream) {
  const float* x    = (const float*)d_in[0];
  const void*  ei   = d_in[1];
  const float* ea   = (const float*)d_in[2];
  const float* g1   = (const float*)d_in[3];
  const float* mu1  = (const float*)d_in[4];
  const float* sig1 = (const float*)d_in[5];
  const float* root1= (const float*)d_in[6];
  const float* b1   = (const float*)d_in[7];
  const float* gam1 = (const float*)d_in[8];
  const float* bet1 = (const float*)d_in[9];
  const float* g2   = (const float*)d_in[10];
  const float* mu2  = (const float*)d_in[11];
  const float* sig2 = (const float*)d_in[12];
  const float* root2= (const float*)d_in[13];
  const float* b2   = (const float*)d_in[14];
  const float* gam2 = (const float*)d_in[15];
  const float* bet2 = (const float*)d_in[16];
  const float* gs   = (const float*)d_in[17];
  const float* mus  = (const float*)d_in[18];
  const float* sigs = (const float*)d_in[19];
  const float* roots= (const float*)d_in[20];
  const float* bs   = (const float*)d_in[21];
  const float* gams = (const float*)d_in[22];
  const float* bets = (const float*)d_in[23];

  int N = in_sizes[0] / 64;
  int E = in_sizes[1] / 2;

  char* w = (char*)d_ws;
  auto alloc = [&](size_t bytes) {
    char* p = w;
    w += (bytes + 255) & ~(size_t)255;
    return p;
  };
  int*   flag    = (int*)alloc(256);
  int*   cnt     = (int*)alloc((size_t)N * 4);
  int*   row_ptr = (int*)alloc((size_t)(N + 1) * 4);
  int*   partials= (int*)alloc(256 * 4);
  int*   pos     = (int*)alloc((size_t)E * 4);
  float* wbuf1   = (float*)alloc((size_t)E * 8 * 4);    // layer1+sc edge records
  float* wbuf2   = (float*)alloc((size_t)E * 8 * 4);    // layer2 edge records
  float* Abuf    = (float*)alloc((size_t)N * 384 * 4);  // agg outputs
  float* h       = (float*)alloc((size_t)N * 64 * 4);
  float* h2      = (float*)alloc((size_t)N * 64 * 4);
  float* scb     = (float*)alloc((size_t)N * 64 * 4);
  float* B1cat   = (float*)alloc(384 * 64 * 4);
  float* B2cat   = (float*)alloc(384 * 64 * 4);
  float* Bsc     = (float*)alloc(128 * 64 * 4);
  float* stats   = (float*)alloc(12 * 64 * 4);

  hipMemsetAsync(cnt, 0, (size_t)N * 4, stream);
  hipMemsetAsync(stats, 0, 12 * 64 * 4, stream);

  int eb = (E + 255) / 256;
  int nb1 = (N + 2047) / 2048;

  prep_cat<<<(6 * 4096 + 255) / 256, 256, 0, stream>>>(g1, root1, B1cat, 5);
  prep_cat<<<(6 * 4096 + 255) / 256, 256, 0, stream>>>(g2, root2, B2cat, 5);
  prep_cat<<<(2 * 4096 + 255) / 256, 256, 0, stream>>>(gs, roots, Bsc, 1);

  detect_kernel<<<1, 256, 0, stream>>>(ei, flag);
  hist_kernel<<<eb, 256, 0, stream>>>(ei, E, flag, cnt, pos);
  scan1<<<nb1, 256, 0, stream>>>(cnt, row_ptr, partials, N);
  scan2<<<1, 256, 0, stream>>>(partials, nb1, row_ptr, N);
  scan3<<<(N + 255) / 256, 256, 0, stream>>>(row_ptr, partials, N);
  scatter_wgt<<<eb, 256, 0, stream>>>(ei, ea, E, flag, row_ptr, pos,
                                      mu1, sig1, mus, sigs, mu2, sig2, wbuf1, wbuf2);

  int m128 = (N + 127) / 128;
  int nb_node = (N + 3) / 4;
  int nb_elem = (N * 64 + 255) / 256;

  // ---- layer1 + shortcut ----
  agg_pre<6><<<nb_node, 256, 0, stream>>>(x, row_ptr, wbuf1, Abuf, N, 384);
  gemm_fused<<<m128, 256, 0, stream>>>(Abuf, 384, 320, x, B1cat, b1, h, N,
                                       stats + 0 * 64, stats + 1 * 64);
  gemm_fused<<<m128, 256, 0, stream>>>(Abuf + 320, 384, 64, x, Bsc, bs, scb, N,
                                       stats + 4 * 64, stats + 5 * 64);
  bn_final<<<1, 64, 0, stream>>>(stats + 0 * 64, stats + 1 * 64, gam1, bet1, N,
                                 stats + 6 * 64, stats + 7 * 64);
  norm_elu<<<nb_elem, 256, 0, stream>>>(h, stats + 6 * 64, stats + 7 * 64, N * 64);

  // ---- layer2 ----
  agg_pre<5><<<nb_node, 256, 0, stream>>>(h, row_ptr, wbuf2, Abuf, N, 320);
  gemm_fused<<<m128, 256, 0, stream>>>(Abuf, 320, 320, h, B2cat, b2, h2, N,
                                       stats + 2 * 64, stats + 3 * 64);

  bn_final<<<1, 64, 0, stream>>>(stats + 2 * 64, stats + 3 * 64, gam2, bet2, N,
                                 stats + 8 * 64, stats + 9 * 64);
  bn_final<<<1, 64, 0, stream>>>(stats + 4 * 64, stats + 5 * 64, gams, bets, N,
                                 stats + 10 * 64, stats + 11 * 64);

  final_kernel<<<nb_elem, 256, 0, stream>>>(h2, scb, stats + 8 * 64, stats + 9 * 64,
                                            stats + 10 * 64, stats + 11 * 64,
                                            (float*)d_out, N * 64);
}

// Round 7
// 367.437 us; speedup vs baseline: 1.1733x; 1.1733x over previous
//
#include <hip/hip_runtime.h>
#include <hip/hip_bf16.h>

// ---------------------------------------------------------------------------
// ResidualBlock: GMMConv(x)->BN->ELU->GMMConv->BN  +  GMMConv_sc(x)->BN ; ELU
// N=50000, E=800000, C=64, K_main=5, K_sc=1.
// Round 7: GEMM reverted to 64x64 tile / 4x4 micro (round-6 128-tile killed
// occupancy: 55KB LDS, 8% occ, 90us). Abuf intermediate now bf16 (halves agg
// writes + GEMM A1 reads; exact decode, RNE encode). scatter_wgt fusion kept.
// ---------------------------------------------------------------------------

#define EPS_SIGMA 1e-15f
#define BN_EPS    1e-5f

typedef unsigned short ushortT;
typedef unsigned int uintT;

__device__ __forceinline__ ushortT f2bf(float f) {
  uintT b = __float_as_uint(f);
  b += 0x7FFFu + ((b >> 16) & 1u);   // round-to-nearest-even
  return (ushortT)(b >> 16);
}
__device__ __forceinline__ float bf2f(ushortT u) {
  return __uint_as_float(((uintT)u) << 16);
}

// --- dtype detect: int64 edge_index has all-zero high words -----------------
__global__ void detect_kernel(const void* ei, int* flag) {
  const int* p = (const int*)ei;
  __shared__ int bad;
  if (threadIdx.x == 0) bad = 0;
  __syncthreads();
  if (p[threadIdx.x * 2 + 1] != 0) atomicAdd(&bad, 1);
  __syncthreads();
  if (threadIdx.x == 0) *flag = (bad == 0);  // 1 => int64 layout
}

__device__ __forceinline__ int load_idx(const void* ei, size_t pos, int is64) {
  if (is64) return (int)((const long long*)ei)[pos];
  return ((const int*)ei)[pos];
}

// --- CSR build: hist also records each edge's within-bucket position --------
__global__ void hist_kernel(const void* ei, int E, const int* flag, int* cnt,
                            int* __restrict__ pos) {
  int e = blockIdx.x * blockDim.x + threadIdx.x;
  if (e >= E) return;
  int d = load_idx(ei, (size_t)E + e, *flag);
  pos[e] = atomicAdd(&cnt[d], 1);
}

__global__ __launch_bounds__(256) void scan1(const int* __restrict__ cnt,
                                             int* __restrict__ row_ptr,
                                             int* __restrict__ partials, int n) {
  int tid = threadIdx.x;
  int base = blockIdx.x * 2048 + tid * 8;
  int v[8], pre[8];
  int run = 0;
#pragma unroll
  for (int j = 0; j < 8; ++j) {
    int idx = base + j;
    v[j] = (idx < n) ? cnt[idx] : 0;
    pre[j] = run;
    run += v[j];
  }
  __shared__ int sd[256];
  sd[tid] = run;
  __syncthreads();
  for (int off = 1; off < 256; off <<= 1) {
    int t = (tid >= off) ? sd[tid - off] : 0;
    __syncthreads();
    sd[tid] += t;
    __syncthreads();
  }
  int excl = sd[tid] - run;
#pragma unroll
  for (int j = 0; j < 8; ++j) {
    int idx = base + j;
    if (idx < n) row_ptr[idx] = excl + pre[j];
  }
  if (tid == 255) partials[blockIdx.x] = sd[255];
}

__global__ void scan2(int* partials, int nb, int* row_ptr, int n) {
  __shared__ int sd[256];
  int tid = threadIdx.x;
  int v = (tid < nb) ? partials[tid] : 0;
  sd[tid] = v;
  __syncthreads();
  for (int off = 1; off < 256; off <<= 1) {
    int t = (tid >= off) ? sd[tid - off] : 0;
    __syncthreads();
    sd[tid] += t;
    __syncthreads();
  }
  if (tid < nb) partials[tid] = sd[tid] - v;
  if (tid == nb - 1) row_ptr[n] = sd[tid];
}

__global__ void scan3(int* __restrict__ row_ptr, const int* __restrict__ partials, int n) {
  int i = blockIdx.x * 256 + threadIdx.x;
  if (i < n) row_ptr[i] += partials[i >> 11];
}

// --- scatter + gaussian weights fused: writes both layers' edge records -----
// wbuf1 rec: {w1_0..w1_3},{w1_4, w_sc, src_bits, 0}   (KT=6 for layer1+sc)
// wbuf2 rec: {w2_0..w2_3},{w2_4, 0,    src_bits, 0}   (KT=5 for layer2)
__global__ __launch_bounds__(256) void scatter_wgt(
    const void* ei, const float* __restrict__ ea, int E, const int* flag,
    const int* __restrict__ row_ptr, const int* __restrict__ pos,
    const float* __restrict__ mu1, const float* __restrict__ sig1,
    const float* __restrict__ mus, const float* __restrict__ sigs,
    const float* __restrict__ mu2, const float* __restrict__ sig2,
    float* __restrict__ wbuf1, float* __restrict__ wbuf2) {
  int e = blockIdx.x * 256 + threadIdx.x;
  if (e >= E) return;
  int is64 = *flag;
  int s = load_idx(ei, (size_t)e, is64);
  int d = load_idx(ei, (size_t)E + e, is64);
  int slot = row_ptr[d] + pos[e];
  float p = ea[e];
  float w1[6], w2[5];
#pragma unroll
  for (int k = 0; k < 5; ++k) {
    float sg = sig1[k], df = p - mu1[k];
    w1[k] = __expf(-0.5f / (EPS_SIGMA + sg * sg) * df * df);
  }
  {
    float sg = sigs[0], df = p - mus[0];
    w1[5] = __expf(-0.5f / (EPS_SIGMA + sg * sg) * df * df);
  }
#pragma unroll
  for (int k = 0; k < 5; ++k) {
    float sg = sig2[k], df = p - mu2[k];
    w2[k] = __expf(-0.5f / (EPS_SIGMA + sg * sg) * df * df);
  }
  float sb = __int_as_float(s);
  float4* o1 = (float4*)wbuf1;
  o1[(size_t)slot * 2 + 0] = make_float4(w1[0], w1[1], w1[2], w1[3]);
  o1[(size_t)slot * 2 + 1] = make_float4(w1[4], w1[5], sb, 0.f);
  float4* o2 = (float4*)wbuf2;
  o2[(size_t)slot * 2 + 0] = make_float4(w2[0], w2[1], w2[2], w2[3]);
  o2[(size_t)slot * 2 + 1] = make_float4(w2[4], 0.f, sb, 0.f);
}

// --- aggregation: wave per node, lane = channel, 8 edges in flight ----------
// Output written as bf16 (intermediate only feeds GEMM A-operand).
template <int KT>
__device__ __forceinline__ void agg_fma(float* acc, float4 wa, float4 wb, float xv) {
  acc[0] = fmaf(wa.x, xv, acc[0]);
  if (KT > 1) acc[1] = fmaf(wa.y, xv, acc[1]);
  if (KT > 2) acc[2] = fmaf(wa.z, xv, acc[2]);
  if (KT > 3) acc[3] = fmaf(wa.w, xv, acc[3]);
  if (KT > 4) acc[4] = fmaf(wb.x, xv, acc[4]);
  if (KT > 5) acc[5] = fmaf(wb.y, xv, acc[5]);
}

template <int KT>
__global__ __launch_bounds__(256) void agg_pre(const float* __restrict__ feat,
                                               const int* __restrict__ row_ptr,
                                               const float* __restrict__ wbuf,
                                               ushortT* __restrict__ out, int n, int ldo) {
  int node = blockIdx.x * 4 + (threadIdx.x >> 6);
  int lane = threadIdx.x & 63;
  if (node >= n) return;
  int beg = row_ptr[node], end = row_ptr[node + 1];
  float acc[KT];
#pragma unroll
  for (int k = 0; k < KT; ++k) acc[k] = 0.f;
  const float4* w4 = (const float4*)wbuf;
  int i = beg;
  for (; i + 8 <= end; i += 8) {
    float4 wa[8], wb[8];
#pragma unroll
    for (int j = 0; j < 8; ++j) {
      wa[j] = w4[(size_t)(i + j) * 2 + 0];
      wb[j] = w4[(size_t)(i + j) * 2 + 1];
    }
    float xv[8];
#pragma unroll
    for (int j = 0; j < 8; ++j)
      xv[j] = feat[(size_t)__float_as_int(wb[j].z) * 64 + lane];
#pragma unroll
    for (int j = 0; j < 8; ++j) agg_fma<KT>(acc, wa[j], wb[j], xv[j]);
  }
  for (; i + 4 <= end; i += 4) {
    float4 wa[4], wb[4];
#pragma unroll
    for (int j = 0; j < 4; ++j) {
      wa[j] = w4[(size_t)(i + j) * 2 + 0];
      wb[j] = w4[(size_t)(i + j) * 2 + 1];
    }
    float xv[4];
#pragma unroll
    for (int j = 0; j < 4; ++j)
      xv[j] = feat[(size_t)__float_as_int(wb[j].z) * 64 + lane];
#pragma unroll
    for (int j = 0; j < 4; ++j) agg_fma<KT>(acc, wa[j], wb[j], xv[j]);
  }
  for (; i < end; ++i) {
    float4 wa = w4[(size_t)i * 2 + 0], wb = w4[(size_t)i * 2 + 1];
    float xv = feat[(size_t)__float_as_int(wb.z) * 64 + lane];
    agg_fma<KT>(acc, wa, wb, xv);
  }
  int degi = end - beg;
  float invdeg = 1.0f / (float)(degi > 1 ? degi : 1);
  size_t o = (size_t)node * ldo + lane;
#pragma unroll
  for (int k = 0; k < KT; ++k) out[o + k * 64] = f2bf(acc[k] * invdeg);
}

// --- weight prep: Bout[(K*64+64) x 64] = [rearranged G ; root] ---------------
__global__ void prep_cat(const float* __restrict__ g, const float* __restrict__ root,
                         float* __restrict__ Bout, int K) {
  int idx = blockIdx.x * 256 + threadIdx.x;
  int total = (K + 1) * 64 * 64;
  if (idx >= total) return;
  int r = idx >> 6, c = idx & 63;
  float v;
  if (r < K * 64) {
    int k = r >> 6, i = r & 63;
    v = g[i * (K * 64) + k * 64 + c];
  } else {
    v = root[(r - K * 64) * 64 + c];
  }
  Bout[idx] = v;
}

// --- GEMM: C[M,64] = [A1(K1 bf16)|A2(64 fp32)]@B + bias ; fused BN stats ----
// 64x64 tile, 4x4 micro (round-5 config: 37KB LDS, 4 blocks/CU).
__global__ __launch_bounds__(256) void gemm_fused(const ushortT* __restrict__ A1, int lda1,
                                                  int K1, const float* __restrict__ A2,
                                                  const float* __restrict__ B,
                                                  const float* __restrict__ bias,
                                                  float* __restrict__ C, int M,
                                                  float* sums, float* sumsq) {
  __shared__ float As[64][68];
  __shared__ float Bs[64][64];
  __shared__ float red[16][64];
  int tile_m = blockIdx.x * 64;
  int tid = threadIdx.x, tx = tid & 15, ty = tid >> 4;
  float acc[4][4] = {};
  int nch = K1 >> 6;
  for (int ch = 0; ch <= nch; ++ch) {
    if (ch < nch) {
      // stage bf16 A1 chunk: 64 rows x 64 cols, 2 passes of 16B/thread
      int kb = ch * 64;
#pragma unroll
      for (int i = 0; i < 2; ++i) {
        int slot = tid + i * 256;          // 0..511
        int r = slot >> 3, c8 = (slot & 7) * 8;
        uint4 v = make_uint4(0u, 0u, 0u, 0u);
        if (tile_m + r < M)
          v = *(const uint4*)&A1[(size_t)(tile_m + r) * lda1 + kb + c8];
        const ushortT* us = (const ushortT*)&v;
        float f[8];
#pragma unroll
        for (int j = 0; j < 8; ++j) f[j] = bf2f(us[j]);
        *(float4*)&As[r][c8]     = make_float4(f[0], f[1], f[2], f[3]);
        *(float4*)&As[r][c8 + 4] = make_float4(f[4], f[5], f[6], f[7]);
      }
    } else {
      // stage fp32 A2 chunk
#pragma unroll
      for (int i = 0; i < 4; ++i) {
        int idx = tid + i * 256, r = idx >> 4, c4 = idx & 15;
        float4 v = make_float4(0.f, 0.f, 0.f, 0.f);
        if (tile_m + r < M) v = *(const float4*)&A2[(size_t)(tile_m + r) * 64 + c4 * 4];
        *(float4*)&As[r][c4 * 4] = v;
      }
    }
#pragma unroll
    for (int i = 0; i < 4; ++i) {
      int idx = tid + i * 256, r = idx >> 4, c4 = idx & 15;
      *(float4*)&Bs[r][c4 * 4] = *(const float4*)&B[(size_t)(ch * 64 + r) * 64 + c4 * 4];
    }
    __syncthreads();
#pragma unroll
    for (int k = 0; k < 64; k += 4) {
      float4 b0 = *(const float4*)&Bs[k + 0][tx * 4];
      float4 b1v = *(const float4*)&Bs[k + 1][tx * 4];
      float4 b2 = *(const float4*)&Bs[k + 2][tx * 4];
      float4 b3 = *(const float4*)&Bs[k + 3][tx * 4];
#pragma unroll
      for (int i = 0; i < 4; ++i) {
        float4 a = *(const float4*)&As[ty * 4 + i][k];
        acc[i][0] = fmaf(a.x, b0.x, acc[i][0]);
        acc[i][1] = fmaf(a.x, b0.y, acc[i][1]);
        acc[i][2] = fmaf(a.x, b0.z, acc[i][2]);
        acc[i][3] = fmaf(a.x, b0.w, acc[i][3]);
        acc[i][0] = fmaf(a.y, b1v.x, acc[i][0]);
        acc[i][1] = fmaf(a.y, b1v.y, acc[i][1]);
        acc[i][2] = fmaf(a.y, b1v.z, acc[i][2]);
        acc[i][3] = fmaf(a.y, b1v.w, acc[i][3]);
        acc[i][0] = fmaf(a.z, b2.x, acc[i][0]);
        acc[i][1] = fmaf(a.z, b2.y, acc[i][1]);
        acc[i][2] = fmaf(a.z, b2.z, acc[i][2]);
        acc[i][3] = fmaf(a.z, b2.w, acc[i][3]);
        acc[i][0] = fmaf(a.w, b3.x, acc[i][0]);
        acc[i][1] = fmaf(a.w, b3.y, acc[i][1]);
        acc[i][2] = fmaf(a.w, b3.z, acc[i][2]);
        acc[i][3] = fmaf(a.w, b3.w, acc[i][3]);
      }
    }
    __syncthreads();
  }
  float cs[4] = {}, cq[4] = {};
#pragma unroll
  for (int i = 0; i < 4; ++i) {
    int r = tile_m + ty * 4 + i;
    if (r < M) {
      int cc = tx * 4;
      float ov[4];
#pragma unroll
      for (int j = 0; j < 4; ++j) {
        ov[j] = acc[i][j] + bias[cc + j];
        cs[j] += ov[j];
        cq[j] = fmaf(ov[j], ov[j], cq[j]);
      }
      *(float4*)&C[(size_t)r * 64 + cc] = make_float4(ov[0], ov[1], ov[2], ov[3]);
    }
  }
#pragma unroll
  for (int j = 0; j < 4; ++j) red[ty][tx * 4 + j] = cs[j];
  __syncthreads();
  if (tid < 64) {
    float t = 0.f;
#pragma unroll
    for (int g = 0; g < 16; ++g) t += red[g][tid];
    atomicAdd(&sums[tid], t);
  }
  __syncthreads();
#pragma unroll
  for (int j = 0; j < 4; ++j) red[ty][tx * 4 + j] = cq[j];
  __syncthreads();
  if (tid < 64) {
    float t = 0.f;
#pragma unroll
    for (int g = 0; g < 16; ++g) t += red[g][tid];
    atomicAdd(&sumsq[tid], t);
  }
}

// --- batchnorm scale/shift + epilogues --------------------------------------
__global__ void bn_final(const float* sum, const float* sumsq, const float* gamma,
                         const float* beta, int n, float* scale, float* shift) {
  int c = threadIdx.x;
  float m = sum[c] / (float)n;
  float v = sumsq[c] / (float)n - m * m;
  float r = rsqrtf(v + BN_EPS);
  float s = r * gamma[c];
  scale[c] = s;
  shift[c] = beta[c] - m * s;
}

__global__ void norm_elu(float* h, const float* __restrict__ scale,
                         const float* __restrict__ shift, int total) {
  int i = blockIdx.x * 256 + threadIdx.x;
  if (i >= total) return;
  int c = i & 63;
  float v = h[i] * scale[c] + shift[c];
  h[i] = v > 0.f ? v : expm1f(v);
}

__global__ void final_kernel(const float* __restrict__ h2, const float* __restrict__ sc,
                             const float* __restrict__ s2, const float* __restrict__ t2,
                             const float* __restrict__ ss, const float* __restrict__ ts,
                             float* __restrict__ out, int total) {
  int i = blockIdx.x * 256 + threadIdx.x;
  if (i >= total) return;
  int c = i & 63;
  float v = h2[i] * s2[c] + t2[c] + sc[i] * ss[c] + ts[c];
  out[i] = v > 0.f ? v : expm1f(v);
}

// ---------------------------------------------------------------------------
extern "C" void kernel_launch(void* const* d_in, const int* in_sizes, int n_in,
                              void* d_out, int out_size, void* d_ws, size_t ws_size,
                              hipStream_t stream) {
  const float* x    = (const float*)d_in[0];
  const void*  ei   = d_in[1];
  const float* ea   = (const float*)d_in[2];
  const float* g1   = (const float*)d_in[3];
  const float* mu1  = (const float*)d_in[4];
  const float* sig1 = (const float*)d_in[5];
  const float* root1= (const float*)d_in[6];
  const float* b1   = (const float*)d_in[7];
  const float* gam1 = (const float*)d_in[8];
  const float* bet1 = (const float*)d_in[9];
  const float* g2   = (const float*)d_in[10];
  const float* mu2  = (const float*)d_in[11];
  const float* sig2 = (const float*)d_in[12];
  const float* root2= (const float*)d_in[13];
  const float* b2   = (const float*)d_in[14];
  const float* gam2 = (const float*)d_in[15];
  const float* bet2 = (const float*)d_in[16];
  const float* gs   = (const float*)d_in[17];
  const float* mus  = (const float*)d_in[18];
  const float* sigs = (const float*)d_in[19];
  const float* roots= (const float*)d_in[20];
  const float* bs   = (const float*)d_in[21];
  const float* gams = (const float*)d_in[22];
  const float* bets = (const float*)d_in[23];

  int N = in_sizes[0] / 64;
  int E = in_sizes[1] / 2;

  char* w = (char*)d_ws;
  auto alloc = [&](size_t bytes) {
    char* p = w;
    w += (bytes + 255) & ~(size_t)255;
    return p;
  };
  int*     flag    = (int*)alloc(256);
  int*     cnt     = (int*)alloc((size_t)N * 4);
  int*     row_ptr = (int*)alloc((size_t)(N + 1) * 4);
  int*     partials= (int*)alloc(256 * 4);
  int*     pos     = (int*)alloc((size_t)E * 4);
  float*   wbuf1   = (float*)alloc((size_t)E * 8 * 4);    // layer1+sc edge records
  float*   wbuf2   = (float*)alloc((size_t)E * 8 * 4);    // layer2 edge records
  ushortT* Abuf    = (ushortT*)alloc((size_t)N * 384 * 2); // agg outputs (bf16)
  float*   h       = (float*)alloc((size_t)N * 64 * 4);
  float*   h2      = (float*)alloc((size_t)N * 64 * 4);
  float*   scb     = (float*)alloc((size_t)N * 64 * 4);
  float*   B1cat   = (float*)alloc(384 * 64 * 4);
  float*   B2cat   = (float*)alloc(384 * 64 * 4);
  float*   Bsc     = (float*)alloc(128 * 64 * 4);
  float*   stats   = (float*)alloc(12 * 64 * 4);

  hipMemsetAsync(cnt, 0, (size_t)N * 4, stream);
  hipMemsetAsync(stats, 0, 12 * 64 * 4, stream);

  int eb = (E + 255) / 256;
  int nb1 = (N + 2047) / 2048;

  prep_cat<<<(6 * 4096 + 255) / 256, 256, 0, stream>>>(g1, root1, B1cat, 5);
  prep_cat<<<(6 * 4096 + 255) / 256, 256, 0, stream>>>(g2, root2, B2cat, 5);
  prep_cat<<<(2 * 4096 + 255) / 256, 256, 0, stream>>>(gs, roots, Bsc, 1);

  detect_kernel<<<1, 256, 0, stream>>>(ei, flag);
  hist_kernel<<<eb, 256, 0, stream>>>(ei, E, flag, cnt, pos);
  scan1<<<nb1, 256, 0, stream>>>(cnt, row_ptr, partials, N);
  scan2<<<1, 256, 0, stream>>>(partials, nb1, row_ptr, N);
  scan3<<<(N + 255) / 256, 256, 0, stream>>>(row_ptr, partials, N);
  scatter_wgt<<<eb, 256, 0, stream>>>(ei, ea, E, flag, row_ptr, pos,
                                      mu1, sig1, mus, sigs, mu2, sig2, wbuf1, wbuf2);

  int mtiles = (N + 63) / 64;
  int nb_node = (N + 3) / 4;
  int nb_elem = (N * 64 + 255) / 256;

  // ---- layer1 + shortcut ----
  agg_pre<6><<<nb_node, 256, 0, stream>>>(x, row_ptr, wbuf1, Abuf, N, 384);
  gemm_fused<<<mtiles, 256, 0, stream>>>(Abuf, 384, 320, x, B1cat, b1, h, N,
                                         stats + 0 * 64, stats + 1 * 64);
  gemm_fused<<<mtiles, 256, 0, stream>>>(Abuf + 320, 384, 64, x, Bsc, bs, scb, N,
                                         stats + 4 * 64, stats + 5 * 64);
  bn_final<<<1, 64, 0, stream>>>(stats + 0 * 64, stats + 1 * 64, gam1, bet1, N,
                                 stats + 6 * 64, stats + 7 * 64);
  norm_elu<<<nb_elem, 256, 0, stream>>>(h, stats + 6 * 64, stats + 7 * 64, N * 64);

  // ---- layer2 ----
  agg_pre<5><<<nb_node, 256, 0, stream>>>(h, row_ptr, wbuf2, Abuf, N, 320);
  gemm_fused<<<mtiles, 256, 0, stream>>>(Abuf, 320, 320, h, B2cat, b2, h2, N,
                                         stats + 2 * 64, stats + 3 * 64);

  bn_final<<<1, 64, 0, stream>>>(stats + 2 * 64, stats + 3 * 64, gam2, bet2, N,
                                 stats + 8 * 64, stats + 9 * 64);
  bn_final<<<1, 64, 0, stream>>>(stats + 4 * 64, stats + 5 * 64, gams, bets, N,
                                 stats + 10 * 64, stats + 11 * 64);

  final_kernel<<<nb_elem, 256, 0, stream>>>(h2, scb, stats + 8 * 64, stats + 9 * 64,
                                            stats + 10 * 64, stats + 11 * 64,
                                            (float*)d_out, N * 64);
}